// Round 19
// baseline (270.547 us; speedup 1.0000x reference)
//
#include <hip/hip_runtime.h>
#include <hip/hip_bf16.h>
#include <hip/hip_cooperative_groups.h>

namespace cg = cooperative_groups;

// z[b, k] = sum_{e : K[e]==k} x[b, I[e]] * y[b, J[e]] * C[e]
// B=2048, DIM=248, N_ENTRIES=60000.
//
// R19: R12's main (best: 44.7us total; 5 alternative mains R13-R18 all equal
// or worse -> family floor) + cooperative single-kernel fusion:
//   phase Z (zero cursors+IJC) -> grid.sync -> phase S (scatter) ->
//   grid.sync -> phase M (R12 bf16 broadcast-gather, stride-16 columns).
// Removes 2 inter-dispatch gaps + launch overheads (~4-5us by ledger), and
// runs Z/S at full-machine width. Grid 1024x512 = exactly 4 blocks/CU
// (LDS 35.8KB x4 = 143KB, VGPR<=64 via __launch_bounds__(512,8)).
// Falls back to the 3-kernel path if cooperative launch is rejected.

#define DIM 248
#define CAP 512      // slots/bucket (mean 242, sigma 15.5; multiple of 16)
#define ROWS 32      // batch rows per main block
#define KS 16        // k-slices per batch group
#define KPB 16       // buckets per slice (covers 256 >= DIM)
#define BLOCK 512    // 8 waves
#define SBLK 256
#define NBUCK 256
#define COLW 16      // dwords per bf16 column (32 rows)

typedef unsigned int uint32;

#define LOF(w) __uint_as_float((w) << 16)
#define HIF(w) __uint_as_float((w) & 0xFFFF0000u)

#define ZERO_WORDS (4096 + NBUCK * CAP * 2)        // 266240 dwords
#define ZERO_VECS  (ZERO_WORDS / 4)                // 66560 int4 stores

// round-to-nearest-even f32 -> bf16 bits
__device__ __forceinline__ uint32 bf16rne(float f) {
  const uint32 u = __float_as_uint(f);
  return (u + 0x7FFFu + ((u >> 16) & 1u)) >> 16;
}

// ---------------- main body (shared by fused phase M and split k_main) ----
__device__ __forceinline__ void main_body(
    const float* __restrict__ x, const float* __restrict__ y,
    const int2* __restrict__ IJC, const uint32* __restrict__ cur,
    float* __restrict__ z, int B, int bid, int tid,
    uint32* xs16, uint32* ys16, uint32* rp) {
  const int t = tid;
  const int group = bid / KS;   // 32-row group
  const int slice = bid % KS;   // k-slice
  const int b0 = group * ROWS;
  const int k0 = slice * KPB;

  // Stage x,y as packed bf16 row-pairs: thread -> row-pair p=t&15, cols c4.
  {
    const int p = t & 15;
    const int bA = b0 + 2 * p < B ? b0 + 2 * p : B - 1;
    const int bB = b0 + 2 * p + 1 < B ? b0 + 2 * p + 1 : B - 1;
    const float* xA = x + (size_t)bA * DIM;
    const float* xB = x + (size_t)bB * DIM;
    const float* yA = y + (size_t)bA * DIM;
    const float* yB = y + (size_t)bB * DIM;
    for (int c4 = t >> 4; c4 < DIM / 4; c4 += BLOCK / 16) {
      const float4 vxa = *(const float4*)(xA + c4 * 4);
      const float4 vxb = *(const float4*)(xB + c4 * 4);
      const float4 vya = *(const float4*)(yA + c4 * 4);
      const float4 vyb = *(const float4*)(yB + c4 * 4);
      const int cb = c4 * 4;
      xs16[(cb + 0) * COLW + p] = bf16rne(vxa.x) | (bf16rne(vxb.x) << 16);
      xs16[(cb + 1) * COLW + p] = bf16rne(vxa.y) | (bf16rne(vxb.y) << 16);
      xs16[(cb + 2) * COLW + p] = bf16rne(vxa.z) | (bf16rne(vxb.z) << 16);
      xs16[(cb + 3) * COLW + p] = bf16rne(vxa.w) | (bf16rne(vxb.w) << 16);
      ys16[(cb + 0) * COLW + p] = bf16rne(vya.x) | (bf16rne(vyb.x) << 16);
      ys16[(cb + 1) * COLW + p] = bf16rne(vya.y) | (bf16rne(vyb.y) << 16);
      ys16[(cb + 2) * COLW + p] = bf16rne(vya.z) | (bf16rne(vyb.z) << 16);
      ys16[(cb + 3) * COLW + p] = bf16rne(vya.w) | (bf16rne(vyb.w) << 16);
    }
  }
  if (t < KPB) {
    const uint32 c = cur[(k0 + t) * 16];   // k0+t < 256: inside cursor region
    rp[t] = c < CAP ? c : CAP;             // 0 for k >= DIM
  }
  __syncthreads();

  const int wave = t >> 6;         // 0..7
  const int lane = t & 63;
  const int s = lane >> 3;         // stream 0..7 (8 lanes each)
  const int u2 = (lane & 7) * 2;   // dword base in column: rows 4u..4u+3

  for (int kk = wave; kk < KPB; kk += 8) {
    const int k = k0 + kk;
    if (k >= DIM) continue;
    const uint32 cnt = rp[kk];
    float a0 = 0.f, a1 = 0.f, a2 = 0.f, a3 = 0.f;

    if (cnt) {
      const uint32 s0 = (uint32)k * CAP;
      const int2* mp = IJC + s0;
      const uint32 cntp = (cnt + 15u) & ~15u;   // pad slots are zeros

      int4 m = *(const int4*)&mp[2 * s];        // entries 2s, 2s+1
      for (uint32 tt = 0; tt < cntp; tt += 16) {
        const int4 mn = *(const int4*)&mp[tt + 16 + 2 * s];   // prefetch
        {
          const uint32 w = (uint32)m.x;
          const uint2 wx = *(const uint2*)&xs16[(w & 0xFFFFu) + u2];
          const uint2 wy = *(const uint2*)&ys16[(w >> 16) + u2];
          const float cc = __int_as_float(m.y);
          a0 = fmaf(LOF(wx.x) * LOF(wy.x), cc, a0);
          a1 = fmaf(HIF(wx.x) * HIF(wy.x), cc, a1);
          a2 = fmaf(LOF(wx.y) * LOF(wy.y), cc, a2);
          a3 = fmaf(HIF(wx.y) * HIF(wy.y), cc, a3);
        }
        {
          const uint32 w = (uint32)m.z;
          const uint2 wx = *(const uint2*)&xs16[(w & 0xFFFFu) + u2];
          const uint2 wy = *(const uint2*)&ys16[(w >> 16) + u2];
          const float cc = __int_as_float(m.w);
          a0 = fmaf(LOF(wx.x) * LOF(wy.x), cc, a0);
          a1 = fmaf(HIF(wx.x) * HIF(wy.x), cc, a1);
          a2 = fmaf(LOF(wx.y) * LOF(wy.y), cc, a2);
          a3 = fmaf(HIF(wx.y) * HIF(wy.y), cc, a3);
        }
        m = mn;
      }
    }

    // reduce across the 8 streams (lane bits 3,4,5)
    a0 += __shfl_xor(a0, 8, 64);   a1 += __shfl_xor(a1, 8, 64);
    a2 += __shfl_xor(a2, 8, 64);   a3 += __shfl_xor(a3, 8, 64);
    a0 += __shfl_xor(a0, 16, 64);  a1 += __shfl_xor(a1, 16, 64);
    a2 += __shfl_xor(a2, 16, 64);  a3 += __shfl_xor(a3, 16, 64);
    a0 += __shfl_xor(a0, 32, 64);  a1 += __shfl_xor(a1, 32, 64);
    a2 += __shfl_xor(a2, 32, 64);  a3 += __shfl_xor(a3, 32, 64);

    if (s == 0) {
      const int bb = b0 + 2 * u2;   // rows 4u..4u+3
      if (bb + 3 < B) {
        float* zp = z + (size_t)bb * DIM + k;
        zp[0] = a0; zp[DIM] = a1; zp[2 * DIM] = a2; zp[3 * DIM] = a3;
      } else {
        if (bb + 0 < B) z[(size_t)(bb + 0) * DIM + k] = a0;
        if (bb + 1 < B) z[(size_t)(bb + 1) * DIM + k] = a1;
        if (bb + 2 < B) z[(size_t)(bb + 2) * DIM + k] = a2;
        if (bb + 3 < B) z[(size_t)(bb + 3) * DIM + k] = a3;
      }
    }
  }
}

// ---------------- fused cooperative kernel: zero -> scatter -> main --------
__global__ __launch_bounds__(BLOCK, 8) void k_fused(
    const float* __restrict__ x, const float* __restrict__ y,
    const int* __restrict__ I, const int* __restrict__ J,
    const int* __restrict__ K, const float* __restrict__ C,
    uint32* cur, int2* IJC, float* __restrict__ z, int n, int B) {
  __shared__ uint32 xs16[DIM * COLW];
  __shared__ uint32 ys16[DIM * COLW];
  __shared__ uint32 rp[KPB];

  cg::grid_group grid = cg::this_grid();
  const size_t gtid = (size_t)blockIdx.x * BLOCK + threadIdx.x;

  // Phase Z: zero cursors (16KB) + IJC (2MB) in one pass
  if (gtid < ZERO_VECS) ((int4*)cur)[gtid] = int4{0, 0, 0, 0};
  grid.sync();

  // Phase S: scatter entries into fixed-capacity buckets
  if (gtid < (size_t)n) {
    const int e = (int)gtid;
    const int k = K[e];
    const uint32 pos = atomicAdd(&cur[k * 16], 1u);
    if (pos < CAP) {
      int2 v;
      v.x = ((I[e] & 255) << 4) | ((J[e] & 255) << 20);  // i*16 | (j*16)<<16
      v.y = __float_as_int(C[e]);
      IJC[(size_t)k * CAP + pos] = v;
    }
  }
  grid.sync();

  // Phase M: broadcast-gather main
  main_body(x, y, IJC, cur, z, B, blockIdx.x, threadIdx.x, xs16, ys16, rp);
}

// ---------------- split-path kernels (fallback if coop launch fails) ------
__global__ __launch_bounds__(SBLK) void k_zero(int4* __restrict__ ws) {
  const int i = blockIdx.x * SBLK + threadIdx.x;
  if (i < ZERO_VECS) ws[i] = int4{0, 0, 0, 0};
}

__global__ __launch_bounds__(SBLK) void k_scatter(
    const int* __restrict__ I, const int* __restrict__ J,
    const int* __restrict__ K, const float* __restrict__ C,
    uint32* __restrict__ cur, int2* __restrict__ IJC, int n) {
  const int e = blockIdx.x * SBLK + threadIdx.x;
  if (e >= n) return;
  const int k = K[e];
  const uint32 pos = atomicAdd(&cur[k * 16], 1u);
  if (pos < CAP) {
    int2 v;
    v.x = ((I[e] & 255) << 4) | ((J[e] & 255) << 20);
    v.y = __float_as_int(C[e]);
    IJC[(size_t)k * CAP + pos] = v;
  }
}

__global__ __launch_bounds__(BLOCK, 8) void k_main(
    const float* __restrict__ x, const float* __restrict__ y,
    const int2* __restrict__ IJC, const uint32* __restrict__ cur,
    float* __restrict__ z, int B) {
  __shared__ uint32 xs16[DIM * COLW];
  __shared__ uint32 ys16[DIM * COLW];
  __shared__ uint32 rp[KPB];
  main_body(x, y, IJC, cur, z, B, blockIdx.x, threadIdx.x, xs16, ys16, rp);
}

// ---------------- last-resort fallback (tiny workspace) -------------------
__global__ __launch_bounds__(SBLK) void k_fallback(
    const float* __restrict__ x, const float* __restrict__ y,
    const int* __restrict__ I, const int* __restrict__ J,
    const int* __restrict__ K, const float* __restrict__ C,
    float* __restrict__ z, int n_entries, int B) {
  __shared__ float4 xs[DIM];
  __shared__ float4 ys[DIM];
  __shared__ float zs[DIM][4];
  const int t = threadIdx.x;
  const int group = blockIdx.x / 4;
  const int slice = blockIdx.x % 4;
  const int b0 = group * 4;
  for (int c = t; c < DIM; c += SBLK) {
    float4 vx, vy;
    vx.x = x[(b0 + 0) * DIM + c];  vy.x = y[(b0 + 0) * DIM + c];
    vx.y = x[(b0 + 1) * DIM + c];  vy.y = y[(b0 + 1) * DIM + c];
    vx.z = x[(b0 + 2) * DIM + c];  vy.z = y[(b0 + 2) * DIM + c];
    vx.w = x[(b0 + 3) * DIM + c];  vy.w = y[(b0 + 3) * DIM + c];
    xs[c] = vx;  ys[c] = vy;
    zs[c][0] = 0.f; zs[c][1] = 0.f; zs[c][2] = 0.f; zs[c][3] = 0.f;
  }
  __syncthreads();
  const int n_per = ((n_entries + 3) / 4 + 3) & ~3;
  int e0 = slice * n_per;  if (e0 > n_entries) e0 = n_entries;
  int e1 = e0 + n_per;     if (e1 > n_entries) e1 = n_entries;
  for (int e = e0 + t; e < e1; e += SBLK) {
    const int ii = I[e], jj = J[e], kk = K[e];
    const float c = C[e];
    const float4 vx = xs[ii], vy = ys[jj];
    atomicAdd(&zs[kk][0], vx.x * vy.x * c);
    atomicAdd(&zs[kk][1], vx.y * vy.y * c);
    atomicAdd(&zs[kk][2], vx.z * vy.z * c);
    atomicAdd(&zs[kk][3], vx.w * vy.w * c);
  }
  __syncthreads();
  for (int i = t; i < 4 * DIM; i += SBLK) {
    const int r = i / DIM, c = i % DIM;
    const int b = b0 + r;
    if (b < B) atomicAdd(&z[b * DIM + c], zs[c][r]);
  }
}

extern "C" void kernel_launch(void* const* d_in, const int* in_sizes, int n_in,
                              void* d_out, int out_size, void* d_ws, size_t ws_size,
                              hipStream_t stream) {
  const float* x = (const float*)d_in[0];
  const float* y = (const float*)d_in[1];
  const int* I = (const int*)d_in[2];
  const int* J = (const int*)d_in[3];
  const int* K = (const int*)d_in[4];
  const float* C = (const float*)d_in[5];
  float* z = (float*)d_out;

  int n = in_sizes[2];
  const int B = in_sizes[0] / DIM;

  // ws: cur[4096 u32] (16KB) | IJC[NBUCK*CAP int2] (2MB)
  const size_t cur_bytes = 4096 * sizeof(uint32);
  const size_t needed = (size_t)ZERO_WORDS * 4 + 256;
  if (ws_size < needed) {
    hipMemsetAsync(d_out, 0, (size_t)B * DIM * sizeof(float), stream);
    const int grid = ((B + 3) / 4) * 4;
    k_fallback<<<grid, SBLK, 0, stream>>>(x, y, I, J, K, C, z, n, B);
    return;
  }

  uint32* cur = (uint32*)d_ws;
  int2* IJC = (int2*)((char*)d_ws + cur_bytes);

  const int groups = (B + ROWS - 1) / ROWS;
  const int grid = groups * KS;    // 1024 for B=2048: exactly 4 blocks/CU

  void* args[] = {(void*)&x, (void*)&y, (void*)&I, (void*)&J, (void*)&K,
                  (void*)&C, (void*)&cur, (void*)&IJC, (void*)&z,
                  (void*)&n, (void*)&B};
  const hipError_t err = hipLaunchCooperativeKernel(
      reinterpret_cast<void*>(k_fused), dim3(grid), dim3(BLOCK), args, 0, stream);

  if (err != hipSuccess) {
    // split path: identical semantics, 3 dispatches
    k_zero<<<(ZERO_VECS + SBLK - 1) / SBLK, SBLK, 0, stream>>>((int4*)d_ws);
    k_scatter<<<(n + SBLK - 1) / SBLK, SBLK, 0, stream>>>(I, J, K, C, cur, IJC, n);
    k_main<<<grid, BLOCK, 0, stream>>>(x, y, IJC, cur, z, B);
  }
}

// Round 20
// 44.581 us; speedup vs baseline: 6.0687x; 6.0687x over previous
//
#include <hip/hip_runtime.h>
#include <hip/hip_bf16.h>

// z[b, k] = sum_{e : K[e]==k} x[b, I[e]] * y[b, J[e]] * C[e]
// B=2048, DIM=248, N_ENTRIES=60000.
//
// R20: exact revert to R12, the measured best (44.7us). R19's coop fusion
// regressed 6x: __launch_bounds__(512,8) forced VGPR 52->32 -> scratch
// spills (VALUBusy 7% at 93% occupancy). R13-R19 structural variants all
// landed >= R12 -> this is the family's empirical floor configuration.
//  - k_zero: cursors (16KB) + IJC (1MB) so bucket pads contribute exact 0.
//  - k_scatter: 1 thread/entry, atomicAdd cursor, packed (i*16|(j*16)<<16, C).
//  - k_main: bf16 LDS columns of 32 rows (16 dwords, stride 16), 8 streams x
//    8 lanes, 2x ds_read_b64 per entry, 1-deep meta prefetch, f32 accum,
//    __shfl_xor reduce, k<DIM guard on compute AND writeback.

#define DIM 248
#define CAP 512      // slots/bucket (mean 242, sigma 15.5; multiple of 16)
#define ROWS 32      // batch rows per main block
#define KS 16        // k-slices per batch group
#define KPB 16       // buckets per slice (covers 256 >= DIM)
#define BLOCK 512    // 8 waves
#define SBLK 256
#define NBUCK 256
#define COLW 16      // dwords per bf16 column (32 rows)

typedef unsigned int uint32;

#define LOF(w) __uint_as_float((w) << 16)
#define HIF(w) __uint_as_float((w) & 0xFFFF0000u)

// ---------- zero: cursors (16KB) + IJC (1MB) ----------
#define ZERO_WORDS (4096 + NBUCK * CAP * 2)        // 266240 dwords
#define ZERO_VECS  (ZERO_WORDS / 4)                // 66560 int4 stores
__global__ __launch_bounds__(SBLK) void k_zero(int4* __restrict__ ws) {
  const int i = blockIdx.x * SBLK + threadIdx.x;
  if (i < ZERO_VECS) ws[i] = int4{0, 0, 0, 0};
}

// ---------- scatter: 1 thread/entry, atomic cursor, fixed-capacity buckets ----------
__global__ __launch_bounds__(SBLK) void k_scatter(
    const int* __restrict__ I, const int* __restrict__ J,
    const int* __restrict__ K, const float* __restrict__ C,
    uint32* __restrict__ cur, int2* __restrict__ IJC, int n) {
  const int e = blockIdx.x * SBLK + threadIdx.x;
  if (e >= n) return;
  const int k = K[e];
  const uint32 pos = atomicAdd(&cur[k * 16], 1u);   // cursors 64 B apart
  if (pos < CAP) {
    int2 v;
    v.x = ((I[e] & 255) << 4) | ((J[e] & 255) << 20);  // i*16 | (j*16)<<16
    v.y = __float_as_int(C[e]);
    IJC[(size_t)k * CAP + pos] = v;
  }
}

// round-to-nearest-even f32 -> bf16 bits (inputs are finite normals)
__device__ __forceinline__ uint32 bf16rne(float f) {
  const uint32 u = __float_as_uint(f);
  return (u + 0x7FFFu + ((u >> 16) & 1u)) >> 16;
}

// ---------- main: bf16 broadcast-gather, full-column b64 reads, prefetch ----------
__global__ __launch_bounds__(BLOCK, 2) void k_main(
    const float* __restrict__ x, const float* __restrict__ y,
    const int2* __restrict__ IJC, const uint32* __restrict__ cur,
    float* __restrict__ z, int B) {
  __shared__ uint32 xs16[DIM * COLW];   // xs16[c*16 + d] = bf16 rows (2d,2d+1)
  __shared__ uint32 ys16[DIM * COLW];
  __shared__ uint32 rp[KPB];

  const int t = threadIdx.x;
  const int group = blockIdx.x / KS;   // 32-row group
  const int slice = blockIdx.x % KS;   // k-slice
  const int b0 = group * ROWS;
  const int k0 = slice * KPB;

  // Stage x,y as packed bf16 row-pairs. Thread: row-pair p=t&15, col-group c4.
  {
    const int p = t & 15;
    const int bbA = b0 + 2 * p < B ? b0 + 2 * p : B - 1;
    const int bbB = b0 + 2 * p + 1 < B ? b0 + 2 * p + 1 : B - 1;
    const float* xA = x + (size_t)bbA * DIM;
    const float* xB = x + (size_t)bbB * DIM;
    const float* yA = y + (size_t)bbA * DIM;
    const float* yB = y + (size_t)bbB * DIM;
    for (int c4 = t >> 4; c4 < DIM / 4; c4 += BLOCK / 16) {
      const float4 vxa = *(const float4*)(xA + c4 * 4);
      const float4 vxb = *(const float4*)(xB + c4 * 4);
      const float4 vya = *(const float4*)(yA + c4 * 4);
      const float4 vyb = *(const float4*)(yB + c4 * 4);
      const int cb = c4 * 4;
      xs16[(cb + 0) * COLW + p] = bf16rne(vxa.x) | (bf16rne(vxb.x) << 16);
      xs16[(cb + 1) * COLW + p] = bf16rne(vxa.y) | (bf16rne(vxb.y) << 16);
      xs16[(cb + 2) * COLW + p] = bf16rne(vxa.z) | (bf16rne(vxb.z) << 16);
      xs16[(cb + 3) * COLW + p] = bf16rne(vxa.w) | (bf16rne(vxb.w) << 16);
      ys16[(cb + 0) * COLW + p] = bf16rne(vya.x) | (bf16rne(vyb.x) << 16);
      ys16[(cb + 1) * COLW + p] = bf16rne(vya.y) | (bf16rne(vyb.y) << 16);
      ys16[(cb + 2) * COLW + p] = bf16rne(vya.z) | (bf16rne(vyb.z) << 16);
      ys16[(cb + 3) * COLW + p] = bf16rne(vya.w) | (bf16rne(vyb.w) << 16);
    }
  }
  if (t < KPB) {
    const int k = k0 + t;
    const uint32 c = (k < DIM) ? cur[k * 16] : 0u;
    rp[t] = c < CAP ? c : CAP;
  }
  __syncthreads();

  const int wave = t >> 6;        // 0..7
  const int lane = t & 63;
  const int s = lane >> 3;        // stream 0..7 (8 lanes each)
  const int u2 = (lane & 7) * 2;  // dword base within column (rows 4u..4u+3)

  for (int kk = wave; kk < KPB; kk += 8) {
    const int k = k0 + kk;
    if (k >= DIM) continue;
    const uint32 s0 = (uint32)k * CAP;
    const uint32 cnt = rp[kk];
    const uint32 cntp = (cnt + 15u) & ~15u;   // <= CAP; pad slots are zeros
    float a0 = 0.f, a1 = 0.f, a2 = 0.f, a3 = 0.f;

    if (cntp) {
      // stream s handles entries tt+2s, tt+2s+1 (one int4 per lane, 8-lane bcast)
      int4 m = *(const int4*)&IJC[s0 + 2 * s];
      for (uint32 tt = 0; tt < cntp; tt += 16) {
        const int4 mn = *(const int4*)&IJC[s0 + tt + 16 + 2 * s];  // prefetch
        {
          const uint32 iw = ((uint32)m.x & 0xFFFFu) + u2;
          const uint32 jw = ((uint32)m.x >> 16) + u2;
          const uint2 wx = *(const uint2*)&xs16[iw];
          const uint2 wy = *(const uint2*)&ys16[jw];
          const float cc = __int_as_float(m.y);
          a0 = fmaf(LOF(wx.x) * LOF(wy.x), cc, a0);
          a1 = fmaf(HIF(wx.x) * HIF(wy.x), cc, a1);
          a2 = fmaf(LOF(wx.y) * LOF(wy.y), cc, a2);
          a3 = fmaf(HIF(wx.y) * HIF(wy.y), cc, a3);
        }
        {
          const uint32 iw = ((uint32)m.z & 0xFFFFu) + u2;
          const uint32 jw = ((uint32)m.z >> 16) + u2;
          const uint2 wx = *(const uint2*)&xs16[iw];
          const uint2 wy = *(const uint2*)&ys16[jw];
          const float cc = __int_as_float(m.w);
          a0 = fmaf(LOF(wx.x) * LOF(wy.x), cc, a0);
          a1 = fmaf(HIF(wx.x) * HIF(wy.x), cc, a1);
          a2 = fmaf(LOF(wx.y) * LOF(wy.y), cc, a2);
          a3 = fmaf(HIF(wx.y) * HIF(wy.y), cc, a3);
        }
        m = mn;
      }
    }

    // reduce across the 8 streams (lane bits 3,4,5)
    a0 += __shfl_xor(a0, 8, 64);   a1 += __shfl_xor(a1, 8, 64);
    a2 += __shfl_xor(a2, 8, 64);   a3 += __shfl_xor(a3, 8, 64);
    a0 += __shfl_xor(a0, 16, 64);  a1 += __shfl_xor(a1, 16, 64);
    a2 += __shfl_xor(a2, 16, 64);  a3 += __shfl_xor(a3, 16, 64);
    a0 += __shfl_xor(a0, 32, 64);  a1 += __shfl_xor(a1, 32, 64);
    a2 += __shfl_xor(a2, 32, 64);  a3 += __shfl_xor(a3, 32, 64);

    if (s == 0) {
      const int bb = b0 + 2 * u2;   // rows 4u..4u+3
      if (bb + 3 < B) {
        float* zp = z + (size_t)bb * DIM + k;
        zp[0] = a0; zp[DIM] = a1; zp[2 * DIM] = a2; zp[3 * DIM] = a3;
      } else {
        if (bb + 0 < B) z[(size_t)(bb + 0) * DIM + k] = a0;
        if (bb + 1 < B) z[(size_t)(bb + 1) * DIM + k] = a1;
        if (bb + 2 < B) z[(size_t)(bb + 2) * DIM + k] = a2;
        if (bb + 3 < B) z[(size_t)(bb + 3) * DIM + k] = a3;
      }
    }
  }
}

// ---------- Fallback (R2 kernel) if workspace is too small ----------
__global__ __launch_bounds__(SBLK) void k_fallback(
    const float* __restrict__ x, const float* __restrict__ y,
    const int* __restrict__ I, const int* __restrict__ J,
    const int* __restrict__ K, const float* __restrict__ C,
    float* __restrict__ z, int n_entries, int B) {
  __shared__ float4 xs[DIM];
  __shared__ float4 ys[DIM];
  __shared__ float zs[DIM][4];
  const int t = threadIdx.x;
  const int group = blockIdx.x / 4;
  const int slice = blockIdx.x % 4;
  const int b0 = group * 4;
  for (int c = t; c < DIM; c += SBLK) {
    float4 vx, vy;
    vx.x = x[(b0 + 0) * DIM + c];  vy.x = y[(b0 + 0) * DIM + c];
    vx.y = x[(b0 + 1) * DIM + c];  vy.y = y[(b0 + 1) * DIM + c];
    vx.z = x[(b0 + 2) * DIM + c];  vy.z = y[(b0 + 2) * DIM + c];
    vx.w = x[(b0 + 3) * DIM + c];  vy.w = y[(b0 + 3) * DIM + c];
    xs[c] = vx;  ys[c] = vy;
    zs[c][0] = 0.f; zs[c][1] = 0.f; zs[c][2] = 0.f; zs[c][3] = 0.f;
  }
  __syncthreads();
  const int n_per = ((n_entries + 3) / 4 + 3) & ~3;
  int e0 = slice * n_per;  if (e0 > n_entries) e0 = n_entries;
  int e1 = e0 + n_per;     if (e1 > n_entries) e1 = n_entries;
  for (int e = e0 + t; e < e1; e += SBLK) {
    const int ii = I[e], jj = J[e], kk = K[e];
    const float c = C[e];
    const float4 vx = xs[ii], vy = ys[jj];
    atomicAdd(&zs[kk][0], vx.x * vy.x * c);
    atomicAdd(&zs[kk][1], vx.y * vy.y * c);
    atomicAdd(&zs[kk][2], vx.z * vy.z * c);
    atomicAdd(&zs[kk][3], vx.w * vy.w * c);
  }
  __syncthreads();
  for (int i = t; i < 4 * DIM; i += SBLK) {
    const int r = i / DIM, c = i % DIM;
    const int b = b0 + r;
    if (b < B) atomicAdd(&z[b * DIM + c], zs[c][r]);
  }
}

extern "C" void kernel_launch(void* const* d_in, const int* in_sizes, int n_in,
                              void* d_out, int out_size, void* d_ws, size_t ws_size,
                              hipStream_t stream) {
  const float* x = (const float*)d_in[0];
  const float* y = (const float*)d_in[1];
  const int* I = (const int*)d_in[2];
  const int* J = (const int*)d_in[3];
  const int* K = (const int*)d_in[4];
  const float* C = (const float*)d_in[5];
  float* z = (float*)d_out;

  const int n = in_sizes[2];
  const int B = in_sizes[0] / DIM;

  // ws: cur[4096 u32] (16KB) | IJC[NBUCK*CAP int2] (1MB) | prefetch slack
  const size_t cur_bytes = 4096 * sizeof(uint32);
  const size_t needed = (size_t)ZERO_WORDS * 4 + 256;
  if (ws_size < needed) {
    hipMemsetAsync(d_out, 0, (size_t)B * DIM * sizeof(float), stream);
    const int grid = ((B + 3) / 4) * 4;
    k_fallback<<<grid, SBLK, 0, stream>>>(x, y, I, J, K, C, z, n, B);
    return;
  }

  uint32* cur = (uint32*)d_ws;
  int2* IJC = (int2*)((char*)d_ws + cur_bytes);

  k_zero<<<(ZERO_VECS + SBLK - 1) / SBLK, SBLK, 0, stream>>>((int4*)d_ws);
  k_scatter<<<(n + SBLK - 1) / SBLK, SBLK, 0, stream>>>(I, J, K, C, cur, IJC, n);

  const int groups = (B + ROWS - 1) / ROWS;
  k_main<<<groups * KS, BLOCK, 0, stream>>>(x, y, IJC, cur, z, B);
}